// Round 18
// baseline (236.100 us; speedup 1.0000x reference)
//
#include <hip/hip_runtime.h>
#include <hip/hip_bf16.h>
#include <cstdint>

#define B_SZ   2
#define S_LEN  2048
#define C_LEN  2048
#define T_LEN  4096
#define EMB_   1024
#define HEADS_ 16
#define D_     64

typedef __attribute__((ext_vector_type(8))) short bf16x8;
typedef __attribute__((ext_vector_type(4))) float f32x4;
typedef __attribute__((ext_vector_type(16))) float f32x16;
typedef __attribute__((ext_vector_type(2))) float f32x2;

__device__ __forceinline__ unsigned short f2bf(float f) {
    unsigned u = __builtin_bit_cast(unsigned, f);
    u += 0x7fffu + ((u >> 16) & 1u);
    return (unsigned short)(u >> 16);
}
__device__ __forceinline__ float bf2f(unsigned short h) {
    return __builtin_bit_cast(float, (unsigned)h << 16);
}

// ------------------- merged prep: xcb build + mask concat + 4x wtrans
// blocks [0,4096): xcb ; [4096,5120): wtrans ; [5120,5152): mcat
__global__ void prep_k(const float* __restrict__ x, const float* __restrict__ ctx,
                       unsigned short* __restrict__ xcb,
                       const float* __restrict__ mask, const float* __restrict__ cmask,
                       float* __restrict__ Mcat,
                       const float* __restrict__ W0, const float* __restrict__ W1,
                       const float* __restrict__ W2, const float* __restrict__ W3,
                       unsigned short* __restrict__ T0, unsigned short* __restrict__ T1,
                       unsigned short* __restrict__ T2, unsigned short* __restrict__ T3) {
    __shared__ __align__(16) unsigned short tile[64][72];
    int bid = blockIdx.x;
    int tid = threadIdx.x;
    if (bid < 4096) {
        // ---- xcb build: one 8-elem chunk per thread
        int i = bid * 256 + tid;
        size_t e8 = (size_t)i * 8;
        int b = (int)(e8 / ((size_t)T_LEN * EMB_));
        size_t rem = e8 % ((size_t)T_LEN * EMB_);
        int t = (int)(rem / EMB_);
        int c = (int)(rem % EMB_);
        const float* src = (t < S_LEN)
            ? &x[((size_t)b * S_LEN + t) * EMB_ + c]
            : &ctx[((size_t)b * C_LEN + (t - S_LEN)) * EMB_ + c];
        float4 v0 = ((const float4*)src)[0];
        float4 v1 = ((const float4*)src)[1];
        uint4 o;
        o.x = (unsigned)f2bf(v0.x) | ((unsigned)f2bf(v0.y) << 16);
        o.y = (unsigned)f2bf(v0.z) | ((unsigned)f2bf(v0.w) << 16);
        o.z = (unsigned)f2bf(v1.x) | ((unsigned)f2bf(v1.y) << 16);
        o.w = (unsigned)f2bf(v1.z) | ((unsigned)f2bf(v1.w) << 16);
        *(uint4*)&xcb[e8] = o;
    } else if (bid < 5120) {
        // ---- weight transpose+convert
        int idx = bid - 4096;
        int bz = idx >> 8, rm = idx & 255, by = rm >> 4, bx = rm & 15;
        const float* W = (bz == 0) ? W0 : (bz == 1) ? W1 : (bz == 2) ? W2 : W3;
        unsigned short* WT = (bz == 0) ? T0 : (bz == 1) ? T1 : (bz == 2) ? T2 : T3;
#pragma unroll
        for (int r = 0; r < 4; ++r) {
            int id2 = tid + r * 256;
            int row = id2 >> 4, c4 = id2 & 15;
            float4 v = ((const float4*)&W[((size_t)(by * 64 + row)) * EMB_ + bx * 64])[c4];
            tile[row][c4 * 4 + 0] = f2bf(v.x);
            tile[row][c4 * 4 + 1] = f2bf(v.y);
            tile[row][c4 * 4 + 2] = f2bf(v.z);
            tile[row][c4 * 4 + 3] = f2bf(v.w);
        }
        __syncthreads();
#pragma unroll
        for (int r = 0; r < 2; ++r) {
            int id2 = tid + r * 256;
            int n = id2 >> 3, k8 = id2 & 7;
            uint4 o;
            unsigned q[4];
#pragma unroll
            for (int j = 0; j < 4; ++j)
                q[j] = (unsigned)tile[k8 * 8 + 2 * j][n] | ((unsigned)tile[k8 * 8 + 2 * j + 1][n] << 16);
            o.x = q[0]; o.y = q[1]; o.z = q[2]; o.w = q[3];
            *(uint4*)&WT[((size_t)(bx * 64 + n)) * EMB_ + by * 64 + k8 * 8] = o;
        }
    } else {
        // ---- mask concat
        int i = (bid - 5120) * 256 + tid;
        int b = i / T_LEN, t = i % T_LEN;
        Mcat[i] = (t < S_LEN) ? mask[(size_t)b * S_LEN + t]
                              : cmask[(size_t)b * C_LEN + (t - S_LEN)];
    }
}

// --------------- fused QKV GEMM + per-head LN + mask-fold + fragment pack
__global__ __launch_bounds__(256) void gemm_qkv_fused_k(
    const unsigned short* __restrict__ A,     // xcb [8192][1024]
    const unsigned short* __restrict__ Bt,    // [3072][1024]
    unsigned short* __restrict__ KF,
    unsigned short* __restrict__ VF,
    unsigned short* __restrict__ Qb,
    const float* __restrict__ qlnw, const float* __restrict__ qlnb,
    const float* __restrict__ klnw, const float* __restrict__ klnb,
    const float* __restrict__ Mcat,
    float kscale, float qscale) {
    constexpr int KTOT = 1024;
    int nt = blockIdx.x, mt = blockIdx.y;
    if (nt >= 16 && (mt & 31) >= 16) return;  // Q over context rows: no output
    __shared__ __align__(16) unsigned short As[128 * 32];
    __shared__ __align__(16) unsigned short Bs[128 * 32];
    int in_row0 = mt * 128;
    int mode = (nt < 8) ? 0 : (nt < 16) ? 1 : 2;   // K, V, Q
    int col0 = (mode == 0) ? nt * 128 : (mode == 1) ? (nt - 8) * 128 : (nt - 16) * 128;
    int tid = threadIdx.x, w = tid >> 6, l = tid & 63, l15 = l & 15, lg = l >> 4;
    int wr = (w >> 1) * 64, wc = (w & 1) * 64;

    f32x4 zero4 = {0.f, 0.f, 0.f, 0.f};
    f32x4 acc[4][4];
#pragma unroll
    for (int i = 0; i < 4; ++i)
#pragma unroll
        for (int j = 0; j < 4; ++j) acc[i][j] = zero4;

    for (int k0 = 0; k0 < KTOT; k0 += 32) {
#pragma unroll
        for (int j = 0; j < 2; ++j) {
            int o = tid * 16 + j * 4096;
            int row = o >> 6;
            int ke = (o & 63) >> 1;
            __builtin_amdgcn_global_load_lds(
                (const __attribute__((address_space(1))) void*)&A[(size_t)(in_row0 + row) * KTOT + k0 + ke],
                (__attribute__((address_space(3))) void*)&As[o >> 1], 16, 0, 0);
            __builtin_amdgcn_global_load_lds(
                (const __attribute__((address_space(1))) void*)&Bt[(size_t)(nt * 128 + row) * KTOT + k0 + ke],
                (__attribute__((address_space(3))) void*)&Bs[o >> 1], 16, 0, 0);
        }
        __syncthreads();
        bf16x8 af[4], bf[4];
#pragma unroll
        for (int fr = 0; fr < 4; ++fr)
            af[fr] = *(const bf16x8*)&As[(wr + fr * 16 + l15) * 32 + lg * 8];
#pragma unroll
        for (int fc = 0; fc < 4; ++fc)
            bf[fc] = *(const bf16x8*)&Bs[(wc + fc * 16 + l15) * 32 + lg * 8];
#pragma unroll
        for (int fr = 0; fr < 4; ++fr)
#pragma unroll
            for (int fc = 0; fc < 4; ++fc)
                acc[fr][fc] = __builtin_amdgcn_mfma_f32_16x16x32_bf16(af[fr], bf[fc], acc[fr][fc], 0, 0, 0);
        __syncthreads();
    }

    // ---------------- fused epilogue: LN (K,Q) + mask fold + pack ----------
    int h = (col0 + wc) >> 6;                  // this wave's head
    float lwv[4], lbv[4];
    if (mode == 0) {
#pragma unroll
        for (int fc = 0; fc < 4; ++fc) { lwv[fc] = klnw[fc * 16 + l15]; lbv[fc] = klnb[fc * 16 + l15]; }
    } else if (mode == 2) {
#pragma unroll
        for (int fc = 0; fc < 4; ++fc) { lwv[fc] = qlnw[fc * 16 + l15]; lbv[fc] = qlnb[fc * 16 + l15]; }
    }
#pragma unroll
    for (int fr = 0; fr < 4; ++fr) {
#pragma unroll
        for (int i = 0; i < 4; ++i) {
            float mu = 0.f, rstd = 0.f;
            if (mode != 1) {
                float s  = acc[fr][0][i] + acc[fr][1][i] + acc[fr][2][i] + acc[fr][3][i];
                float s2 = acc[fr][0][i] * acc[fr][0][i] + acc[fr][1][i] * acc[fr][1][i]
                         + acc[fr][2][i] * acc[fr][2][i] + acc[fr][3][i] * acc[fr][3][i];
#pragma unroll
                for (int m = 1; m <= 8; m <<= 1) {
                    s  += __shfl_xor(s, m);
                    s2 += __shfl_xor(s2, m);
                }
                mu = s * (1.f / 64.f);
                float var = s2 * (1.f / 64.f) - mu * mu;
                rstd = rsqrtf(var + 1e-5f);
            }
            if (mode == 2) {                   // ---- Q: LN + qscale*mq, row layout
                int r = (mt & 31) * 128 + wr + fr * 16 + lg * 4 + i;
                int bq = mt >> 5;
                float mq = Mcat[(size_t)bq * T_LEN + r];
                size_t bh = (size_t)(bq * HEADS_ + h);
#pragma unroll
                for (int fc = 0; fc < 4; ++fc) {
                    int dh = fc * 16 + l15;
                    float o = (acc[fr][fc][i] - mu) * rstd * lwv[fc] + lbv[fc];
                    Qb[(bh * S_LEN + r) * 64 + dh] = f2bf(o * qscale * mq);
                }
            } else {
                int grow = in_row0 + wr + fr * 16 + lg * 4 + i;
                int bb = grow >> 12, t = grow & 4095;
                float mt_ = Mcat[(size_t)bb * T_LEN + t];
                size_t bh = (size_t)(bb * HEADS_ + h);
                int kt = t >> 5, t31 = t & 31;
                if (mode == 0) {               // ---- K: LN + kscale*mt, frag pack
#pragma unroll
                    for (int fc = 0; fc < 4; ++fc) {
                        int dh = fc * 16 + l15;
                        float o = (acc[fr][fc][i] - mu) * rstd * lwv[fc] + lbv[fc];
                        size_t flat = (((bh * 128 + kt) * 4 + (dh >> 4)) * 64
                                       + ((dh >> 3) & 1) * 32 + t31) * 8 + (dh & 7);
                        KF[flat] = f2bf(o * kscale * mt_);
                    }
                } else {                       // ---- V: *mt, sigma frag pack
                    int f1 = (t31 >> 4) & 1;
                    int j = ((t31 >> 3) & 1) * 4 + (t31 & 3);
                    int lofs = ((t31 >> 2) & 1) * 32;
#pragma unroll
                    for (int fc = 0; fc < 4; ++fc) {
                        int dh = fc * 16 + l15;
                        int f = (dh >> 5) * 2 + f1;
                        int ll = lofs + (dh & 31);
                        size_t flat = (((bh * 128 + kt) * 4 + f) * 64 + ll) * 8 + j;
                        VF[flat] = f2bf(acc[fr][fc][i] * mt_);
                    }
                }
            }
        }
    }
}

// --------------------------- final projection GEMM, 64-row tiles (2 blk/CU)
__global__ __launch_bounds__(256) void gemm_bt64_k(
    const unsigned short* __restrict__ A,     // [4096][1024]
    const unsigned short* __restrict__ Bt,    // [1024][1024]
    float* __restrict__ Cout,
    const float* __restrict__ bias) {
    constexpr int KTOT = 1024, NTOT = 1024;
    __shared__ __align__(16) unsigned short As[64 * 32];
    __shared__ __align__(16) unsigned short Bs[128 * 32];
    int nt = blockIdx.x, mt = blockIdx.y;
    int row0 = mt * 64;
    int tid = threadIdx.x, w = tid >> 6, l = tid & 63, l15 = l & 15, lg = l >> 4;
    int wr = (w >> 1) * 32, wc = (w & 1) * 64;

    f32x4 zero4 = {0.f, 0.f, 0.f, 0.f};
    f32x4 acc[2][4];
#pragma unroll
    for (int i = 0; i < 2; ++i)
#pragma unroll
        for (int j = 0; j < 4; ++j) acc[i][j] = zero4;

    for (int k0 = 0; k0 < KTOT; k0 += 32) {
        {
            int o = tid * 16;                   // 4KB A tile: one load/thread
            int row = o >> 6;
            int ke = (o & 63) >> 1;
            __builtin_amdgcn_global_load_lds(
                (const __attribute__((address_space(1))) void*)&A[(size_t)(row0 + row) * KTOT + k0 + ke],
                (__attribute__((address_space(3))) void*)&As[o >> 1], 16, 0, 0);
        }
#pragma unroll
        for (int j = 0; j < 2; ++j) {           // 8KB B tile: two loads/thread
            int o = tid * 16 + j * 4096;
            int row = o >> 6;
            int ke = (o & 63) >> 1;
            __builtin_amdgcn_global_load_lds(
                (const __attribute__((address_space(1))) void*)&Bt[(size_t)(nt * 128 + row) * KTOT + k0 + ke],
                (__attribute__((address_space(3))) void*)&Bs[o >> 1], 16, 0, 0);
        }
        __syncthreads();
        bf16x8 af[2], bf[4];
#pragma unroll
        for (int fr = 0; fr < 2; ++fr)
            af[fr] = *(const bf16x8*)&As[(wr + fr * 16 + l15) * 32 + lg * 8];
#pragma unroll
        for (int fc = 0; fc < 4; ++fc)
            bf[fc] = *(const bf16x8*)&Bs[(wc + fc * 16 + l15) * 32 + lg * 8];
#pragma unroll
        for (int fr = 0; fr < 2; ++fr)
#pragma unroll
            for (int fc = 0; fc < 4; ++fc)
                acc[fr][fc] = __builtin_amdgcn_mfma_f32_16x16x32_bf16(af[fr], bf[fc], acc[fr][fc], 0, 0, 0);
        __syncthreads();
    }
#pragma unroll
    for (int fr = 0; fr < 2; ++fr) {
#pragma unroll
        for (int fc = 0; fc < 4; ++fc) {
            int row = row0 + wr + fr * 16 + lg * 4;
            int col = nt * 128 + wc + fc * 16 + l15;
#pragma unroll
            for (int i = 0; i < 4; ++i)
                Cout[(size_t)(row + i) * NTOT + col] = acc[fr][fc][i] + bias[col];
        }
    }
}

// ---------------------------------------------------------- flash attention
// r13/r15 structure: 4-buffer K+V LDS ring, 2 kt tiles per barrier interval,
// two independent chains, max-free softmax, masks pre-folded. NEW: s_setprio
// around MFMA clusters (T5) — the 2 waves/SIMD come from different blocks at
// independent phases, so priority arbitration has room to help (m191 regime).
#define SOFTMAX(SA, MT, LS, PB0, PB1) do {                                        \
    f32x2 e2[8];                                                                  \
    _Pragma("unroll") for (int i_ = 0; i_ < 8; ++i_) {                            \
        e2[i_][0] = __builtin_amdgcn_exp2f(SA[2 * i_]);                           \
        e2[i_][1] = __builtin_amdgcn_exp2f(SA[2 * i_ + 1]);                       \
    }                                                                             \
    {                                                                             \
        float rsA_ = 0.f, rsB_ = 0.f;                                             \
        _Pragma("unroll") for (int i_ = 0; i_ < 8; ++i_) {                        \
            rsA_ = fmaf(e2[i_][0], MT[2 * i_], rsA_);                             \
            rsB_ = fmaf(e2[i_][1], MT[2 * i_ + 1], rsB_);                         \
        }                                                                         \
        float rs_ = rsA_ + rsB_;                                                  \
        rs_ += __shfl_xor(rs_, 32);                                               \
        (LS) += rs_;                                                              \
    }                                                                             \
    unsigned pk_[8];                                                              \
    _Pragma("unroll") for (int d_ = 0; d_ < 8; ++d_)                              \
        asm("v_cvt_pk_bf16_f32 %0, %1, %2" : "=v"(pk_[d_])                        \
            : "v"(e2[d_][0]), "v"(e2[d_][1]));                                    \
    { uint4 u0_; u0_.x=pk_[0]; u0_.y=pk_[1]; u0_.z=pk_[2]; u0_.w=pk_[3];          \
      uint4 u1_; u1_.x=pk_[4]; u1_.y=pk_[5]; u1_.z=pk_[6]; u1_.w=pk_[7];          \
      (PB0) = __builtin_bit_cast(bf16x8, u0_);                                    \
      (PB1) = __builtin_bit_cast(bf16x8, u1_); }                                  \
} while (0)

__global__ __launch_bounds__(256) void attn32_k(
    const unsigned short* __restrict__ Q,    // [B,H,S,64], pre-scaled (log2e, mq)
    const unsigned short* __restrict__ KF,   // fragment-packed K (mt folded)
    const unsigned short* __restrict__ VF,   // fragment-packed V^T (mt folded)
    const float* __restrict__ Mcat,          // [B,T]
    unsigned short* __restrict__ O) {        // [B,S,EMB]
    __shared__ __align__(16) unsigned short Ks[4][2048];   // 4KB per buf
    __shared__ __align__(16) unsigned short Vs[4][2048];
    __shared__ float OldsF[4][64][32];                     // 32KB epilogue
    __shared__ float Llds[4][32];

    // XCD swizzle: each XCD owns 4 consecutive bh -> K/V fits its private L2.
    int bid = blockIdx.x;                      // 512 blocks
    int xcd = bid & 7, slot = bid >> 3;        // 8 XCDs x 64 slots
    int bh = xcd * 4 + (slot >> 4);            // 4 bh per XCD
    int qblk = slot & 15;                      // 16 q-blocks of 128 rows
    int b = bh >> 4, h = bh & 15;
    int tid = threadIdx.x;
    int w = tid >> 6;
    int lane = tid & 63;
    int l31 = lane & 31;
    int hi = lane >> 5;
    int q0 = qblk * 128;
    int qw = q0 + w * 32;                      // this wave's first q row

    const unsigned short* KFb_ = KF + (size_t)bh * 262144;
    const unsigned short* VFb_ = VF + (size_t)bh * 262144;
    const float* Mb = Mcat + (size_t)b * T_LEN;

    // Q fragments (held for whole kernel): 32 q rows per wave
    bf16x8 qf[4];
    {
        const unsigned short* Qp = Q + ((size_t)bh * S_LEN + qw + l31) * 64 + hi * 8;
#pragma unroll
        for (int s = 0; s < 4; ++s) qf[s] = *(const bf16x8*)(Qp + s * 16);
    }

    f32x16 Z16;
#pragma unroll
    for (int i = 0; i < 16; ++i) Z16[i] = 0.f;
    f32x16 acc0 = Z16, acc1 = Z16;             // O^T: d 0..31 / 32..63 x 32 q
    float lS = 0.f;

#define STAGE(BUF, KT) do {                                                        \
    __builtin_amdgcn_global_load_lds(                                              \
        (const __attribute__((address_space(1))) void*)(KFb_ + (size_t)(KT) * 2048 + tid * 8), \
        (__attribute__((address_space(3))) void*)&Ks[BUF][tid * 8], 16, 0, 0);     \
    __builtin_amdgcn_global_load_lds(                                              \
        (const __attribute__((address_space(1))) void*)(VFb_ + (size_t)(KT) * 2048 + tid * 8), \
        (__attribute__((address_space(3))) void*)&Vs[BUF][tid * 8], 16, 0, 0);     \
} while (0)

    STAGE(0, 0); STAGE(1, 1);
    __syncthreads();

    for (int it = 0; it < 64; ++it) {
        int base = (it & 1) << 1;              // compute bufs {base, base+1}
        int kt0 = it * 2;
        if (it < 63) {                          // stage next pair into other bufs
            STAGE(base ^ 2, kt0 + 2);
            STAGE((base ^ 2) + 1, kt0 + 3);
        }
        // --- t-mask loads for both tiles (denominator only) ---
        const float* mb0 = Mb + kt0 * 32 + 4 * hi;
        float4 am0 = *(const float4*)(mb0);
        float4 am1 = *(const float4*)(mb0 + 8);
        float4 am2 = *(const float4*)(mb0 + 16);
        float4 am3 = *(const float4*)(mb0 + 24);
        float4 bm0 = *(const float4*)(mb0 + 32);
        float4 bm1 = *(const float4*)(mb0 + 40);
        float4 bm2 = *(const float4*)(mb0 + 48);
        float4 bm3 = *(const float4*)(mb0 + 56);
        // --- LDS -> fragment regs (linear 16B/lane) ---
        bf16x8 kfrA[4], vfrA[4], kfrB[4], vfrB[4];
#pragma unroll
        for (int s = 0; s < 4; ++s) {
            kfrA[s] = *(const bf16x8*)&Ks[base][s * 512 + lane * 8];
            vfrA[s] = *(const bf16x8*)&Vs[base][s * 512 + lane * 8];
            kfrB[s] = *(const bf16x8*)&Ks[base + 1][s * 512 + lane * 8];
            vfrB[s] = *(const bf16x8*)&Vs[base + 1][s * 512 + lane * 8];
        }
        // --- S^T = K · Q^T : two independent chains (setprio around MFMA) ---
        f32x16 saA = Z16, saB = Z16;
        __builtin_amdgcn_s_setprio(1);
#pragma unroll
        for (int s = 0; s < 4; ++s) {
            saA = __builtin_amdgcn_mfma_f32_32x32x16_bf16(kfrA[s], qf[s], saA, 0, 0, 0);
            saB = __builtin_amdgcn_mfma_f32_32x32x16_bf16(kfrB[s], qf[s], saB, 0, 0, 0);
        }
        __builtin_amdgcn_s_setprio(0);
        float mtA_[16], mtB_[16];
        mtA_[0] = am0.x; mtA_[1] = am0.y; mtA_[2]  = am0.z; mtA_[3]  = am0.w;
        mtA_[4] = am1.x; mtA_[5] = am1.y; mtA_[6]  = am1.z; mtA_[7]  = am1.w;
        mtA_[8] = am2.x; mtA_[9] = am2.y; mtA_[10] = am2.z; mtA_[11] = am2.w;
        mtA_[12] = am3.x; mtA_[13] = am3.y; mtA_[14] = am3.z; mtA_[15] = am3.w;
        mtB_[0] = bm0.x; mtB_[1] = bm0.y; mtB_[2]  = bm0.z; mtB_[3]  = bm0.w;
        mtB_[4] = bm1.x; mtB_[5] = bm1.y; mtB_[6]  = bm1.z; mtB_[7]  = bm1.w;
        mtB_[8] = bm2.x; mtB_[9] = bm2.y; mtB_[10] = bm2.z; mtB_[11] = bm2.w;
        mtB_[12] = bm3.x; mtB_[13] = bm3.y; mtB_[14] = bm3.z; mtB_[15] = bm3.w;
        // --- softmax (two chains; compiler interleaves) ---
        bf16x8 p0A, p1A, p0B, p1B;
        SOFTMAX(saA, mtA_, lS, p0A, p1A);
        SOFTMAX(saB, mtB_, lS, p0B, p1B);
        // --- O^T += V^T · P^T for both tiles (setprio around MFMA) ---
        __builtin_amdgcn_s_setprio(1);
        acc0 = __builtin_amdgcn_mfma_f32_32x32x16_bf16(vfrA[0], p0A, acc0, 0, 0, 0);
        acc1 = __builtin_amdgcn_mfma_f32_32x32x16_bf16(vfrA[2], p0A, acc1, 0, 0, 0);
        acc0 = __builtin_amdgcn_mfma_f32_32x32x16_bf16(vfrA[1], p1A, acc0, 0, 0, 0);
        acc1 = __builtin_amdgcn_mfma_f32_32x32x16_bf16(vfrA[3], p1A, acc1, 0, 0, 0);
        acc0 = __builtin_amdgcn_mfma_f32_32x32x16_bf16(vfrB[0], p0B, acc0, 0, 0, 0);
        acc1 = __builtin_amdgcn_mfma_f32_32x32x16_bf16(vfrB[2], p0B, acc1, 0, 0, 0);
        acc0 = __builtin_amdgcn_mfma_f32_32x32x16_bf16(vfrB[1], p1B, acc0, 0, 0, 0);
        acc1 = __builtin_amdgcn_mfma_f32_32x32x16_bf16(vfrB[3], p1B, acc1, 0, 0, 0);
        __builtin_amdgcn_s_setprio(0);
        __syncthreads();   // reads of pair done; staged pair drained
    }
#undef STAGE

    // --- per-wave epilogue: LDS transpose for coalesced O writes ---
#pragma unroll
    for (int r = 0; r < 16; ++r) {
        int dl = (r & 3) + 8 * (r >> 2) + 4 * hi;
        OldsF[w][dl][l31] = acc0[r];
        OldsF[w][dl + 32][l31] = acc1[r];
    }
    if (hi == 0) Llds[w][l31] = lS;
    __syncthreads();
    {
        int rr = lane >> 1, hf = lane & 1;     // lane -> (q row, d half)
        float L = Llds[w][rr];
        float invL = 1.f / (L + 1e-13f);
        float mqz = Mb[q0 + w * 32 + rr];      // zero out rows with mq == 0
        invL = (mqz != 0.f) ? invL : 0.f;
        float v_[32];
#pragma unroll
        for (int dd = 0; dd < 32; ++dd)
            v_[dd] = OldsF[w][hf * 32 + dd][rr] * invL;
        unsigned po_[16];
#pragma unroll
        for (int d2 = 0; d2 < 16; ++d2)
            asm("v_cvt_pk_bf16_f32 %0, %1, %2" : "=v"(po_[d2]) : "v"(v_[2*d2]), "v"(v_[2*d2+1]));
        unsigned short* Orow = &O[((size_t)b * S_LEN + qw + rr) * EMB_ + h * 64 + hf * 32];
#pragma unroll
        for (int i = 0; i < 4; ++i) {
            uint4 st;
            st.x = po_[4*i]; st.y = po_[4*i+1]; st.z = po_[4*i+2]; st.w = po_[4*i+3];
            *(uint4*)(Orow + i * 8) = st;
        }
    }
}

// ------------------------------------------------------------------ launch
extern "C" void kernel_launch(void* const* d_in, const int* in_sizes, int n_in,
                              void* d_out, int out_size, void* d_ws, size_t ws_size,
                              hipStream_t stream) {
    const float* x     = (const float*)d_in[0];
    const float* ctx   = (const float*)d_in[1];
    const float* mask  = (const float*)d_in[2];
    const float* cmask = (const float*)d_in[3];
    const float* Wq    = (const float*)d_in[4];
    const float* Wk    = (const float*)d_in[5];
    const float* Wv    = (const float*)d_in[6];
    const float* Wu    = (const float*)d_in[7];
    const float* bu    = (const float*)d_in[8];
    const float* qlnw  = (const float*)d_in[9];
    const float* qlnb  = (const float*)d_in[10];
    const float* klnw  = (const float*)d_in[11];
    const float* klnb  = (const float*)d_in[12];

    unsigned short* ws = (unsigned short*)d_ws;
    unsigned short* xcb = ws + 0;               //  8,388,608 elems; dead after QKV
    unsigned short* WkT = ws + 8388608;         //  contiguous K|V|Q for fused GEMM
    unsigned short* WvT = ws + 9437184;
    unsigned short* WqT = ws + 10485760;
    unsigned short* WuT = ws + 12582912;        //  lives to the end
    unsigned short* Qb  = ws + 13631488;        //  4,194,304 (fused GEMM output)
    unsigned short* KFb = ws + 17825792;        //  8,388,608
    unsigned short* VFb = ws + 26214400;        //  8,388,608
    unsigned short* Ob  = ws + 0;               //  attn output over dead xcb
    float* Mcat         = (float*)(ws + 34603008);  // 8192 floats

    const float scale = 0.17677669529663687f;               // 1024^-0.25
    const float qscale = 0.17677669529663687f * 1.4426950408889634f; // * log2(e)

    prep_k<<<5152, 256, 0, stream>>>(x, ctx, xcb, mask, cmask, Mcat,
                                     Wk, Wv, Wq, Wu, WkT, WvT, WqT, WuT);

    gemm_qkv_fused_k<<<dim3(24, 64), 256, 0, stream>>>(
        xcb, WkT, KFb, VFb, Qb, qlnw, qlnb, klnw, klnb, Mcat, scale, qscale);

    attn32_k<<<512, 256, 0, stream>>>(Qb, KFb, VFb, Mcat, Ob);

    gemm_bt64_k<<<dim3(8, 64), 256, 0, stream>>>(Ob, WuT, (float*)d_out, bu);
}

// Round 19
// 224.566 us; speedup vs baseline: 1.0514x; 1.0514x over previous
//
#include <hip/hip_runtime.h>
#include <hip/hip_bf16.h>
#include <cstdint>

#define B_SZ   2
#define S_LEN  2048
#define C_LEN  2048
#define T_LEN  4096
#define EMB_   1024
#define HEADS_ 16
#define D_     64

typedef __attribute__((ext_vector_type(8))) short bf16x8;
typedef __attribute__((ext_vector_type(4))) float f32x4;
typedef __attribute__((ext_vector_type(16))) float f32x16;
typedef __attribute__((ext_vector_type(2))) float f32x2;

__device__ __forceinline__ unsigned short f2bf(float f) {
    unsigned u = __builtin_bit_cast(unsigned, f);
    u += 0x7fffu + ((u >> 16) & 1u);
    return (unsigned short)(u >> 16);
}
__device__ __forceinline__ float bf2f(unsigned short h) {
    return __builtin_bit_cast(float, (unsigned)h << 16);
}

// ------------------- merged prep: xcb build + mask concat + 4x wtrans
// blocks [0,4096): xcb ; [4096,5120): wtrans ; [5120,5152): mcat
__global__ void prep_k(const float* __restrict__ x, const float* __restrict__ ctx,
                       unsigned short* __restrict__ xcb,
                       const float* __restrict__ mask, const float* __restrict__ cmask,
                       float* __restrict__ Mcat,
                       const float* __restrict__ W0, const float* __restrict__ W1,
                       const float* __restrict__ W2, const float* __restrict__ W3,
                       unsigned short* __restrict__ T0, unsigned short* __restrict__ T1,
                       unsigned short* __restrict__ T2, unsigned short* __restrict__ T3) {
    __shared__ __align__(16) unsigned short tile[64][72];
    int bid = blockIdx.x;
    int tid = threadIdx.x;
    if (bid < 4096) {
        // ---- xcb build: one 8-elem chunk per thread
        int i = bid * 256 + tid;
        size_t e8 = (size_t)i * 8;
        int b = (int)(e8 / ((size_t)T_LEN * EMB_));
        size_t rem = e8 % ((size_t)T_LEN * EMB_);
        int t = (int)(rem / EMB_);
        int c = (int)(rem % EMB_);
        const float* src = (t < S_LEN)
            ? &x[((size_t)b * S_LEN + t) * EMB_ + c]
            : &ctx[((size_t)b * C_LEN + (t - S_LEN)) * EMB_ + c];
        float4 v0 = ((const float4*)src)[0];
        float4 v1 = ((const float4*)src)[1];
        uint4 o;
        o.x = (unsigned)f2bf(v0.x) | ((unsigned)f2bf(v0.y) << 16);
        o.y = (unsigned)f2bf(v0.z) | ((unsigned)f2bf(v0.w) << 16);
        o.z = (unsigned)f2bf(v1.x) | ((unsigned)f2bf(v1.y) << 16);
        o.w = (unsigned)f2bf(v1.z) | ((unsigned)f2bf(v1.w) << 16);
        *(uint4*)&xcb[e8] = o;
    } else if (bid < 5120) {
        // ---- weight transpose+convert
        int idx = bid - 4096;
        int bz = idx >> 8, rm = idx & 255, by = rm >> 4, bx = rm & 15;
        const float* W = (bz == 0) ? W0 : (bz == 1) ? W1 : (bz == 2) ? W2 : W3;
        unsigned short* WT = (bz == 0) ? T0 : (bz == 1) ? T1 : (bz == 2) ? T2 : T3;
#pragma unroll
        for (int r = 0; r < 4; ++r) {
            int id2 = tid + r * 256;
            int row = id2 >> 4, c4 = id2 & 15;
            float4 v = ((const float4*)&W[((size_t)(by * 64 + row)) * EMB_ + bx * 64])[c4];
            tile[row][c4 * 4 + 0] = f2bf(v.x);
            tile[row][c4 * 4 + 1] = f2bf(v.y);
            tile[row][c4 * 4 + 2] = f2bf(v.z);
            tile[row][c4 * 4 + 3] = f2bf(v.w);
        }
        __syncthreads();
#pragma unroll
        for (int r = 0; r < 2; ++r) {
            int id2 = tid + r * 256;
            int n = id2 >> 3, k8 = id2 & 7;
            uint4 o;
            unsigned q[4];
#pragma unroll
            for (int j = 0; j < 4; ++j)
                q[j] = (unsigned)tile[k8 * 8 + 2 * j][n] | ((unsigned)tile[k8 * 8 + 2 * j + 1][n] << 16);
            o.x = q[0]; o.y = q[1]; o.z = q[2]; o.w = q[3];
            *(uint4*)&WT[((size_t)(bx * 64 + n)) * EMB_ + by * 64 + k8 * 8] = o;
        }
    } else {
        // ---- mask concat
        int i = (bid - 5120) * 256 + tid;
        int b = i / T_LEN, t = i % T_LEN;
        Mcat[i] = (t < S_LEN) ? mask[(size_t)b * S_LEN + t]
                              : cmask[(size_t)b * C_LEN + (t - S_LEN)];
    }
}

// --------------- fused QKV GEMM + per-head LN + mask-fold + fragment pack
__global__ __launch_bounds__(256) void gemm_qkv_fused_k(
    const unsigned short* __restrict__ A,     // xcb [8192][1024]
    const unsigned short* __restrict__ Bt,    // [3072][1024]
    unsigned short* __restrict__ KF,
    unsigned short* __restrict__ VF,
    unsigned short* __restrict__ Qb,
    const float* __restrict__ qlnw, const float* __restrict__ qlnb,
    const float* __restrict__ klnw, const float* __restrict__ klnb,
    const float* __restrict__ Mcat,
    float kscale, float qscale) {
    constexpr int KTOT = 1024;
    int nt = blockIdx.x, mt = blockIdx.y;
    if (nt >= 16 && (mt & 31) >= 16) return;  // Q over context rows: no output
    __shared__ __align__(16) unsigned short As[128 * 32];
    __shared__ __align__(16) unsigned short Bs[128 * 32];
    int in_row0 = mt * 128;
    int mode = (nt < 8) ? 0 : (nt < 16) ? 1 : 2;   // K, V, Q
    int col0 = (mode == 0) ? nt * 128 : (mode == 1) ? (nt - 8) * 128 : (nt - 16) * 128;
    int tid = threadIdx.x, w = tid >> 6, l = tid & 63, l15 = l & 15, lg = l >> 4;
    int wr = (w >> 1) * 64, wc = (w & 1) * 64;

    f32x4 zero4 = {0.f, 0.f, 0.f, 0.f};
    f32x4 acc[4][4];
#pragma unroll
    for (int i = 0; i < 4; ++i)
#pragma unroll
        for (int j = 0; j < 4; ++j) acc[i][j] = zero4;

    for (int k0 = 0; k0 < KTOT; k0 += 32) {
#pragma unroll
        for (int j = 0; j < 2; ++j) {
            int o = tid * 16 + j * 4096;
            int row = o >> 6;
            int ke = (o & 63) >> 1;
            __builtin_amdgcn_global_load_lds(
                (const __attribute__((address_space(1))) void*)&A[(size_t)(in_row0 + row) * KTOT + k0 + ke],
                (__attribute__((address_space(3))) void*)&As[o >> 1], 16, 0, 0);
            __builtin_amdgcn_global_load_lds(
                (const __attribute__((address_space(1))) void*)&Bt[(size_t)(nt * 128 + row) * KTOT + k0 + ke],
                (__attribute__((address_space(3))) void*)&Bs[o >> 1], 16, 0, 0);
        }
        __syncthreads();
        bf16x8 af[4], bf[4];
#pragma unroll
        for (int fr = 0; fr < 4; ++fr)
            af[fr] = *(const bf16x8*)&As[(wr + fr * 16 + l15) * 32 + lg * 8];
#pragma unroll
        for (int fc = 0; fc < 4; ++fc)
            bf[fc] = *(const bf16x8*)&Bs[(wc + fc * 16 + l15) * 32 + lg * 8];
#pragma unroll
        for (int fr = 0; fr < 4; ++fr)
#pragma unroll
            for (int fc = 0; fc < 4; ++fc)
                acc[fr][fc] = __builtin_amdgcn_mfma_f32_16x16x32_bf16(af[fr], bf[fc], acc[fr][fc], 0, 0, 0);
        __syncthreads();
    }

    // ---------------- fused epilogue: LN (K,Q) + mask fold + pack ----------
    int h = (col0 + wc) >> 6;                  // this wave's head
    float lwv[4], lbv[4];
    if (mode == 0) {
#pragma unroll
        for (int fc = 0; fc < 4; ++fc) { lwv[fc] = klnw[fc * 16 + l15]; lbv[fc] = klnb[fc * 16 + l15]; }
    } else if (mode == 2) {
#pragma unroll
        for (int fc = 0; fc < 4; ++fc) { lwv[fc] = qlnw[fc * 16 + l15]; lbv[fc] = qlnb[fc * 16 + l15]; }
    }
#pragma unroll
    for (int fr = 0; fr < 4; ++fr) {
#pragma unroll
        for (int i = 0; i < 4; ++i) {
            float mu = 0.f, rstd = 0.f;
            if (mode != 1) {
                float s  = acc[fr][0][i] + acc[fr][1][i] + acc[fr][2][i] + acc[fr][3][i];
                float s2 = acc[fr][0][i] * acc[fr][0][i] + acc[fr][1][i] * acc[fr][1][i]
                         + acc[fr][2][i] * acc[fr][2][i] + acc[fr][3][i] * acc[fr][3][i];
#pragma unroll
                for (int m = 1; m <= 8; m <<= 1) {
                    s  += __shfl_xor(s, m);
                    s2 += __shfl_xor(s2, m);
                }
                mu = s * (1.f / 64.f);
                float var = s2 * (1.f / 64.f) - mu * mu;
                rstd = rsqrtf(var + 1e-5f);
            }
            if (mode == 2) {                   // ---- Q: LN + qscale*mq, row layout
                int r = (mt & 31) * 128 + wr + fr * 16 + lg * 4 + i;
                int bq = mt >> 5;
                float mq = Mcat[(size_t)bq * T_LEN + r];
                size_t bh = (size_t)(bq * HEADS_ + h);
#pragma unroll
                for (int fc = 0; fc < 4; ++fc) {
                    int dh = fc * 16 + l15;
                    float o = (acc[fr][fc][i] - mu) * rstd * lwv[fc] + lbv[fc];
                    Qb[(bh * S_LEN + r) * 64 + dh] = f2bf(o * qscale * mq);
                }
            } else {
                int grow = in_row0 + wr + fr * 16 + lg * 4 + i;
                int bb = grow >> 12, t = grow & 4095;
                float mt_ = Mcat[(size_t)bb * T_LEN + t];
                size_t bh = (size_t)(bb * HEADS_ + h);
                int kt = t >> 5, t31 = t & 31;
                if (mode == 0) {               // ---- K: LN + kscale*mt, frag pack
#pragma unroll
                    for (int fc = 0; fc < 4; ++fc) {
                        int dh = fc * 16 + l15;
                        float o = (acc[fr][fc][i] - mu) * rstd * lwv[fc] + lbv[fc];
                        size_t flat = (((bh * 128 + kt) * 4 + (dh >> 4)) * 64
                                       + ((dh >> 3) & 1) * 32 + t31) * 8 + (dh & 7);
                        KF[flat] = f2bf(o * kscale * mt_);
                    }
                } else {                       // ---- V: *mt, sigma frag pack
                    int f1 = (t31 >> 4) & 1;
                    int j = ((t31 >> 3) & 1) * 4 + (t31 & 3);
                    int lofs = ((t31 >> 2) & 1) * 32;
#pragma unroll
                    for (int fc = 0; fc < 4; ++fc) {
                        int dh = fc * 16 + l15;
                        int f = (dh >> 5) * 2 + f1;
                        int ll = lofs + (dh & 31);
                        size_t flat = (((bh * 128 + kt) * 4 + f) * 64 + ll) * 8 + j;
                        VF[flat] = f2bf(acc[fr][fc][i] * mt_);
                    }
                }
            }
        }
    }
}

// --------------------------- final projection GEMM, 64-row tiles (2 blk/CU)
__global__ __launch_bounds__(256) void gemm_bt64_k(
    const unsigned short* __restrict__ A,     // [4096][1024]
    const unsigned short* __restrict__ Bt,    // [1024][1024]
    float* __restrict__ Cout,
    const float* __restrict__ bias) {
    constexpr int KTOT = 1024, NTOT = 1024;
    __shared__ __align__(16) unsigned short As[64 * 32];
    __shared__ __align__(16) unsigned short Bs[128 * 32];
    int nt = blockIdx.x, mt = blockIdx.y;
    int row0 = mt * 64;
    int tid = threadIdx.x, w = tid >> 6, l = tid & 63, l15 = l & 15, lg = l >> 4;
    int wr = (w >> 1) * 32, wc = (w & 1) * 64;

    f32x4 zero4 = {0.f, 0.f, 0.f, 0.f};
    f32x4 acc[2][4];
#pragma unroll
    for (int i = 0; i < 2; ++i)
#pragma unroll
        for (int j = 0; j < 4; ++j) acc[i][j] = zero4;

    for (int k0 = 0; k0 < KTOT; k0 += 32) {
        {
            int o = tid * 16;                   // 4KB A tile: one load/thread
            int row = o >> 6;
            int ke = (o & 63) >> 1;
            __builtin_amdgcn_global_load_lds(
                (const __attribute__((address_space(1))) void*)&A[(size_t)(row0 + row) * KTOT + k0 + ke],
                (__attribute__((address_space(3))) void*)&As[o >> 1], 16, 0, 0);
        }
#pragma unroll
        for (int j = 0; j < 2; ++j) {           // 8KB B tile: two loads/thread
            int o = tid * 16 + j * 4096;
            int row = o >> 6;
            int ke = (o & 63) >> 1;
            __builtin_amdgcn_global_load_lds(
                (const __attribute__((address_space(1))) void*)&Bt[(size_t)(nt * 128 + row) * KTOT + k0 + ke],
                (__attribute__((address_space(3))) void*)&Bs[o >> 1], 16, 0, 0);
        }
        __syncthreads();
        bf16x8 af[2], bf[4];
#pragma unroll
        for (int fr = 0; fr < 2; ++fr)
            af[fr] = *(const bf16x8*)&As[(wr + fr * 16 + l15) * 32 + lg * 8];
#pragma unroll
        for (int fc = 0; fc < 4; ++fc)
            bf[fc] = *(const bf16x8*)&Bs[(wc + fc * 16 + l15) * 32 + lg * 8];
#pragma unroll
        for (int fr = 0; fr < 2; ++fr)
#pragma unroll
            for (int fc = 0; fc < 4; ++fc)
                acc[fr][fc] = __builtin_amdgcn_mfma_f32_16x16x32_bf16(af[fr], bf[fc], acc[fr][fc], 0, 0, 0);
        __syncthreads();
    }
#pragma unroll
    for (int fr = 0; fr < 2; ++fr) {
#pragma unroll
        for (int fc = 0; fc < 4; ++fc) {
            int row = row0 + wr + fr * 16 + lg * 4;
            int col = nt * 128 + wc + fc * 16 + l15;
#pragma unroll
            for (int i = 0; i < 4; ++i)
                Cout[(size_t)(row + i) * NTOT + col] = acc[fr][fc][i] + bias[col];
        }
    }
}

// ---------------------------------------------------------- flash attention
// r13/r15 structure: 4-buffer K+V LDS ring, 2 kt tiles per barrier interval,
// two independent chains, max-free softmax, masks pre-folded.
#define SOFTMAX(SA, MT, LS, PB0, PB1) do {                                        \
    f32x2 e2[8];                                                                  \
    _Pragma("unroll") for (int i_ = 0; i_ < 8; ++i_) {                            \
        e2[i_][0] = __builtin_amdgcn_exp2f(SA[2 * i_]);                           \
        e2[i_][1] = __builtin_amdgcn_exp2f(SA[2 * i_ + 1]);                       \
    }                                                                             \
    {                                                                             \
        float rsA_ = 0.f, rsB_ = 0.f;                                             \
        _Pragma("unroll") for (int i_ = 0; i_ < 8; ++i_) {                        \
            rsA_ = fmaf(e2[i_][0], MT[2 * i_], rsA_);                             \
            rsB_ = fmaf(e2[i_][1], MT[2 * i_ + 1], rsB_);                         \
        }                                                                         \
        float rs_ = rsA_ + rsB_;                                                  \
        rs_ += __shfl_xor(rs_, 32);                                               \
        (LS) += rs_;                                                              \
    }                                                                             \
    unsigned pk_[8];                                                              \
    _Pragma("unroll") for (int d_ = 0; d_ < 8; ++d_)                              \
        asm("v_cvt_pk_bf16_f32 %0, %1, %2" : "=v"(pk_[d_])                        \
            : "v"(e2[d_][0]), "v"(e2[d_][1]));                                    \
    { uint4 u0_; u0_.x=pk_[0]; u0_.y=pk_[1]; u0_.z=pk_[2]; u0_.w=pk_[3];          \
      uint4 u1_; u1_.x=pk_[4]; u1_.y=pk_[5]; u1_.z=pk_[6]; u1_.w=pk_[7];          \
      (PB0) = __builtin_bit_cast(bf16x8, u0_);                                    \
      (PB1) = __builtin_bit_cast(bf16x8, u1_); }                                  \
} while (0)

__global__ __launch_bounds__(256) void attn32_k(
    const unsigned short* __restrict__ Q,    // [B,H,S,64], pre-scaled (log2e, mq)
    const unsigned short* __restrict__ KF,   // fragment-packed K (mt folded)
    const unsigned short* __restrict__ VF,   // fragment-packed V^T (mt folded)
    const float* __restrict__ Mcat,          // [B,T]
    unsigned short* __restrict__ O) {        // [B,S,EMB]
    __shared__ __align__(16) unsigned short Ks[4][2048];   // 4KB per buf
    __shared__ __align__(16) unsigned short Vs[4][2048];
    __shared__ float OldsF[4][64][32];                     // 32KB epilogue
    __shared__ float Llds[4][32];

    // XCD swizzle: each XCD owns 4 consecutive bh -> K/V fits its private L2.
    int bid = blockIdx.x;                      // 512 blocks
    int xcd = bid & 7, slot = bid >> 3;        // 8 XCDs x 64 slots
    int bh = xcd * 4 + (slot >> 4);            // 4 bh per XCD
    int qblk = slot & 15;                      // 16 q-blocks of 128 rows
    int b = bh >> 4, h = bh & 15;
    int tid = threadIdx.x;
    int w = tid >> 6;
    int lane = tid & 63;
    int l31 = lane & 31;
    int hi = lane >> 5;
    int q0 = qblk * 128;
    int qw = q0 + w * 32;                      // this wave's first q row

    const unsigned short* KFb_ = KF + (size_t)bh * 262144;
    const unsigned short* VFb_ = VF + (size_t)bh * 262144;
    const float* Mb = Mcat + (size_t)b * T_LEN;

    // Q fragments (held for whole kernel): 32 q rows per wave
    bf16x8 qf[4];
    {
        const unsigned short* Qp = Q + ((size_t)bh * S_LEN + qw + l31) * 64 + hi * 8;
#pragma unroll
        for (int s = 0; s < 4; ++s) qf[s] = *(const bf16x8*)(Qp + s * 16);
    }

    f32x16 Z16;
#pragma unroll
    for (int i = 0; i < 16; ++i) Z16[i] = 0.f;
    f32x16 acc0 = Z16, acc1 = Z16;             // O^T: d 0..31 / 32..63 x 32 q
    float lS = 0.f;

#define STAGE(BUF, KT) do {                                                        \
    __builtin_amdgcn_global_load_lds(                                              \
        (const __attribute__((address_space(1))) void*)(KFb_ + (size_t)(KT) * 2048 + tid * 8), \
        (__attribute__((address_space(3))) void*)&Ks[BUF][tid * 8], 16, 0, 0);     \
    __builtin_amdgcn_global_load_lds(                                              \
        (const __attribute__((address_space(1))) void*)(VFb_ + (size_t)(KT) * 2048 + tid * 8), \
        (__attribute__((address_space(3))) void*)&Vs[BUF][tid * 8], 16, 0, 0);     \
} while (0)

    STAGE(0, 0); STAGE(1, 1);
    __syncthreads();

    for (int it = 0; it < 64; ++it) {
        int base = (it & 1) << 1;              // compute bufs {base, base+1}
        int kt0 = it * 2;
        if (it < 63) {                          // stage next pair into other bufs
            STAGE(base ^ 2, kt0 + 2);
            STAGE((base ^ 2) + 1, kt0 + 3);
        }
        // --- t-mask loads for both tiles (denominator only) ---
        const float* mb0 = Mb + kt0 * 32 + 4 * hi;
        float4 am0 = *(const float4*)(mb0);
        float4 am1 = *(const float4*)(mb0 + 8);
        float4 am2 = *(const float4*)(mb0 + 16);
        float4 am3 = *(const float4*)(mb0 + 24);
        float4 bm0 = *(const float4*)(mb0 + 32);
        float4 bm1 = *(const float4*)(mb0 + 40);
        float4 bm2 = *(const float4*)(mb0 + 48);
        float4 bm3 = *(const float4*)(mb0 + 56);
        // --- LDS -> fragment regs (linear 16B/lane) ---
        bf16x8 kfrA[4], vfrA[4], kfrB[4], vfrB[4];
#pragma unroll
        for (int s = 0; s < 4; ++s) {
            kfrA[s] = *(const bf16x8*)&Ks[base][s * 512 + lane * 8];
            vfrA[s] = *(const bf16x8*)&Vs[base][s * 512 + lane * 8];
            kfrB[s] = *(const bf16x8*)&Ks[base + 1][s * 512 + lane * 8];
            vfrB[s] = *(const bf16x8*)&Vs[base + 1][s * 512 + lane * 8];
        }
        // --- S^T = K · Q^T : two independent chains ---
        f32x16 saA = Z16, saB = Z16;
#pragma unroll
        for (int s = 0; s < 4; ++s) {
            saA = __builtin_amdgcn_mfma_f32_32x32x16_bf16(kfrA[s], qf[s], saA, 0, 0, 0);
            saB = __builtin_amdgcn_mfma_f32_32x32x16_bf16(kfrB[s], qf[s], saB, 0, 0, 0);
        }
        float mtA_[16], mtB_[16];
        mtA_[0] = am0.x; mtA_[1] = am0.y; mtA_[2]  = am0.z; mtA_[3]  = am0.w;
        mtA_[4] = am1.x; mtA_[5] = am1.y; mtA_[6]  = am1.z; mtA_[7]  = am1.w;
        mtA_[8] = am2.x; mtA_[9] = am2.y; mtA_[10] = am2.z; mtA_[11] = am2.w;
        mtA_[12] = am3.x; mtA_[13] = am3.y; mtA_[14] = am3.z; mtA_[15] = am3.w;
        mtB_[0] = bm0.x; mtB_[1] = bm0.y; mtB_[2]  = bm0.z; mtB_[3]  = bm0.w;
        mtB_[4] = bm1.x; mtB_[5] = bm1.y; mtB_[6]  = bm1.z; mtB_[7]  = bm1.w;
        mtB_[8] = bm2.x; mtB_[9] = bm2.y; mtB_[10] = bm2.z; mtB_[11] = bm2.w;
        mtB_[12] = bm3.x; mtB_[13] = bm3.y; mtB_[14] = bm3.z; mtB_[15] = bm3.w;
        // --- softmax (two chains; compiler interleaves) ---
        bf16x8 p0A, p1A, p0B, p1B;
        SOFTMAX(saA, mtA_, lS, p0A, p1A);
        SOFTMAX(saB, mtB_, lS, p0B, p1B);
        // --- O^T += V^T · P^T for both tiles ---
        acc0 = __builtin_amdgcn_mfma_f32_32x32x16_bf16(vfrA[0], p0A, acc0, 0, 0, 0);
        acc1 = __builtin_amdgcn_mfma_f32_32x32x16_bf16(vfrA[2], p0A, acc1, 0, 0, 0);
        acc0 = __builtin_amdgcn_mfma_f32_32x32x16_bf16(vfrA[1], p1A, acc0, 0, 0, 0);
        acc1 = __builtin_amdgcn_mfma_f32_32x32x16_bf16(vfrA[3], p1A, acc1, 0, 0, 0);
        acc0 = __builtin_amdgcn_mfma_f32_32x32x16_bf16(vfrB[0], p0B, acc0, 0, 0, 0);
        acc1 = __builtin_amdgcn_mfma_f32_32x32x16_bf16(vfrB[2], p0B, acc1, 0, 0, 0);
        acc0 = __builtin_amdgcn_mfma_f32_32x32x16_bf16(vfrB[1], p1B, acc0, 0, 0, 0);
        acc1 = __builtin_amdgcn_mfma_f32_32x32x16_bf16(vfrB[3], p1B, acc1, 0, 0, 0);
        __syncthreads();   // reads of pair done; staged pair drained
    }
#undef STAGE

    // --- per-wave epilogue: LDS transpose for coalesced O writes ---
#pragma unroll
    for (int r = 0; r < 16; ++r) {
        int dl = (r & 3) + 8 * (r >> 2) + 4 * hi;
        OldsF[w][dl][l31] = acc0[r];
        OldsF[w][dl + 32][l31] = acc1[r];
    }
    if (hi == 0) Llds[w][l31] = lS;
    __syncthreads();
    {
        int rr = lane >> 1, hf = lane & 1;     // lane -> (q row, d half)
        float L = Llds[w][rr];
        float invL = 1.f / (L + 1e-13f);
        float mqz = Mb[q0 + w * 32 + rr];      // zero out rows with mq == 0
        invL = (mqz != 0.f) ? invL : 0.f;
        float v_[32];
#pragma unroll
        for (int dd = 0; dd < 32; ++dd)
            v_[dd] = OldsF[w][hf * 32 + dd][rr] * invL;
        unsigned po_[16];
#pragma unroll
        for (int d2 = 0; d2 < 16; ++d2)
            asm("v_cvt_pk_bf16_f32 %0, %1, %2" : "=v"(po_[d2]) : "v"(v_[2*d2]), "v"(v_[2*d2+1]));
        unsigned short* Orow = &O[((size_t)b * S_LEN + qw + rr) * EMB_ + h * 64 + hf * 32];
#pragma unroll
        for (int i = 0; i < 4; ++i) {
            uint4 st;
            st.x = po_[4*i]; st.y = po_[4*i+1]; st.z = po_[4*i+2]; st.w = po_[4*i+3];
            *(uint4*)(Orow + i * 8) = st;
        }
    }
}

// ------------------------------------------------------------------ launch
extern "C" void kernel_launch(void* const* d_in, const int* in_sizes, int n_in,
                              void* d_out, int out_size, void* d_ws, size_t ws_size,
                              hipStream_t stream) {
    const float* x     = (const float*)d_in[0];
    const float* ctx   = (const float*)d_in[1];
    const float* mask  = (const float*)d_in[2];
    const float* cmask = (const float*)d_in[3];
    const float* Wq    = (const float*)d_in[4];
    const float* Wk    = (const float*)d_in[5];
    const float* Wv    = (const float*)d_in[6];
    const float* Wu    = (const float*)d_in[7];
    const float* bu    = (const float*)d_in[8];
    const float* qlnw  = (const float*)d_in[9];
    const float* qlnb  = (const float*)d_in[10];
    const float* klnw  = (const float*)d_in[11];
    const float* klnb  = (const float*)d_in[12];

    unsigned short* ws = (unsigned short*)d_ws;
    unsigned short* xcb = ws + 0;               //  8,388,608 elems; dead after QKV
    unsigned short* WkT = ws + 8388608;         //  contiguous K|V|Q for fused GEMM
    unsigned short* WvT = ws + 9437184;
    unsigned short* WqT = ws + 10485760;
    unsigned short* WuT = ws + 12582912;        //  lives to the end
    unsigned short* Qb  = ws + 13631488;        //  4,194,304 (fused GEMM output)
    unsigned short* KFb = ws + 17825792;        //  8,388,608
    unsigned short* VFb = ws + 26214400;        //  8,388,608
    unsigned short* Ob  = ws + 0;               //  attn output over dead xcb
    float* Mcat         = (float*)(ws + 34603008);  // 8192 floats

    const float scale = 0.17677669529663687f;               // 1024^-0.25
    const float qscale = 0.17677669529663687f * 1.4426950408889634f; // * log2(e)

    prep_k<<<5152, 256, 0, stream>>>(x, ctx, xcb, mask, cmask, Mcat,
                                     Wk, Wv, Wq, Wu, WkT, WvT, WqT, WuT);

    gemm_qkv_fused_k<<<dim3(24, 64), 256, 0, stream>>>(
        xcb, WkT, KFb, VFb, Qb, qlnw, qlnb, klnw, klnb, Mcat, scale, qscale);

    attn32_k<<<512, 256, 0, stream>>>(Qb, KFb, VFb, Mcat, Ob);

    gemm_bt64_k<<<dim3(8, 64), 256, 0, stream>>>(Ob, WuT, (float*)d_out, bu);
}